// Round 12
// baseline (207.744 us; speedup 1.0000x reference)
//
#include <hip/hip_runtime.h>

typedef unsigned short u16;
typedef unsigned int u32;
typedef float f32x4 __attribute__((ext_vector_type(4)));
typedef float f32x16 __attribute__((ext_vector_type(16)));
typedef unsigned int u32x2 __attribute__((ext_vector_type(2)));
typedef __bf16 bf16x8 __attribute__((ext_vector_type(8)));

using gas_ptr = const __attribute__((address_space(1))) void*;
using las_ptr = __attribute__((address_space(3))) void*;

#define NH 16
#define HD 64
#define TSEQ 2048

__device__ __forceinline__ u16 f2bf(float f) {
  return __builtin_bit_cast(u16, (__bf16)f);  // v_cvt RNE (pk-fusable)
}
__device__ __forceinline__ u32 pk2bf(float a, float b) {
  return (u32)f2bf(a) | ((u32)f2bf(b) << 16);
}
// exchange: upper-32-lanes of a <-> lower-32-lanes of b (T12 recipe)
__device__ __forceinline__ void pl_swap(u32& a, u32& b) {
  auto r = __builtin_amdgcn_permlane32_swap(a, b, false, false);
  u32x2 rv = __builtin_bit_cast(u32x2, r);
  a = rv[0];
  b = rv[1];
}

// Stage a (NI*THREADS/8)-row x 64-bf16 tile: NI*THREADS 16B-chunks. LDS dest
// linear; global source pre-swizzled with chunk ^= (row&7) so a swizzled
// ds_read is conflict-free (rule #21: both-sides-or-neither).
template <int NI, int THREADS = 256>
__device__ __forceinline__ void stage_rows(const u16* __restrict__ src, size_t rstride,
                                           int row0, int col0, u16* lbuf, int tid) {
#pragma unroll
  for (int i = 0; i < NI; ++i) {
    int p = i * THREADS + tid;
    int r = p >> 3, cst = p & 7;
    int csrc = cst ^ (r & 7);
    const u16* g = src + (size_t)(row0 + r) * rstride + col0 + csrc * 8;
    char* l = (char*)lbuf + (size_t)(i * THREADS + (tid & ~63)) * 16;  // wave-uniform base
    __builtin_amdgcn_global_load_lds((gas_ptr)g, (las_ptr)l, 16, 0, 0);
  }
}

// ---------------- conversion kernels ----------------
__global__ void k_f32_to_bf16(const float* __restrict__ in, u16* __restrict__ out, int n4) {
  int i = blockIdx.x * blockDim.x + threadIdx.x;
  if (i >= n4) return;
  float4 v = ((const float4*)in)[i];
  ((uint2*)out)[i] = make_uint2(pk2bf(v.x, v.y), pk2bf(v.z, v.w));
}

// rope table: [t][j] -> (cos, sin) of t * 10000^(-j/32)
__global__ void k_rope_tab(float2* __restrict__ tab) {
  int i = blockIdx.x * 256 + threadIdx.x;  // 65536 = 2048*32
  int t = i >> 5, j = i & 31;
  float inv = exp2f(-(float)j * 0.41524101186092028f);  // log2(1e4)/32
  float s, c;
  sincosf((float)t * inv, &s, &c);
  tab[i] = make_float2(c, s);
}

// in: [R][C] f32  ->  out: [C][R] bf16   (64x64 tiles)
__global__ void k_transpose_bf16(const float* __restrict__ in, u16* __restrict__ out,
                                 int R, int C) {
  __shared__ u16 lds[64 * 68];
  const int t = threadIdx.x;
  const int c0 = blockIdx.x * 64, r0 = blockIdx.y * 64;
  const int fc = (t & 15) * 4;
#pragma unroll
  for (int p = 0; p < 4; ++p) {
    int r = p * 16 + (t >> 4);
    float4 v = *(const float4*)&in[(size_t)(r0 + r) * C + c0 + fc];
    *(uint2*)&lds[r * 68 + fc] = make_uint2(pk2bf(v.x, v.y), pk2bf(v.z, v.w));
  }
  __syncthreads();
#pragma unroll
  for (int p = 0; p < 16; ++p) {
    int c = p * 4 + (t >> 6);
    int r = t & 63;
    out[(size_t)(c0 + c) * R + r0 + r] = lds[r * 68 + c];
  }
}

// ---------------- GEMM: C[M][N] = A[M][K=1024] * B^T  (B stored [N][K]) ----------------
// MODE 0: QKV projection. Epilogue bounces through LDS for coalesced stores:
//   q -> [b,t,1024] row-major with RoPE applied and pre-scaled by log2(e)/8
//   k -> [b,t,1024] row-major with RoPE
//   v -> [b,h,d,t]  (transposed in LDS, 128B-run stores)
// MODE 1: plain fp32 store to outF[M][N].
template <int MODE>
__global__ __launch_bounds__(256, 2) void k_gemm(const u16* __restrict__ A,
                                                 const u16* __restrict__ B,
                                                 float* __restrict__ outF,
                                                 u16* __restrict__ qb, u16* __restrict__ kb,
                                                 u16* __restrict__ vb,
                                                 const float2* __restrict__ rt, int N) {
  __shared__ __align__(16) u16 SH[32768];  // 64KB: staging dbuf; reused as bounce buffer
  u16* Alb = SH;          // [2][128*64]
  u16* Blb = SH + 16384;  // [2][128*64]
  const int tid = threadIdx.x;
  const int lane = tid & 63;
  const int wv = tid >> 6, wr = wv >> 1, wc = wv & 1;
  const int m0 = blockIdx.y * 128, n0 = blockIdx.x * 128;

  f32x4 acc[4][4] = {};

  stage_rows<4>(A, 1024, m0, 0, Alb, tid);
  stage_rows<4>(B, 1024, n0, 0, Blb, tid);
  __syncthreads();

  for (int kt = 0; kt < 16; ++kt) {
    const int cur = kt & 1;
    if (kt < 15) {
      stage_rows<4>(A, 1024, m0, (kt + 1) * 64, Alb + (cur ^ 1) * 8192, tid);
      stage_rows<4>(B, 1024, n0, (kt + 1) * 64, Blb + (cur ^ 1) * 8192, tid);
    }
#pragma unroll
    for (int ks = 0; ks < 2; ++ks) {
      bf16x8 af[4], bfr[4];
#pragma unroll
      for (int mi = 0; mi < 4; ++mi) {
        int r = wr * 64 + mi * 16 + (lane & 15);
        int ch = (ks * 4 + (lane >> 4)) ^ (r & 7);
        af[mi] = *(const bf16x8*)((const char*)(Alb + cur * 8192) + r * 128 + ch * 16);
      }
#pragma unroll
      for (int ni = 0; ni < 4; ++ni) {
        int r = wc * 64 + ni * 16 + (lane & 15);
        int ch = (ks * 4 + (lane >> 4)) ^ (r & 7);
        bfr[ni] = *(const bf16x8*)((const char*)(Blb + cur * 8192) + r * 128 + ch * 16);
      }
#pragma unroll
      for (int mi = 0; mi < 4; ++mi)
#pragma unroll
        for (int ni = 0; ni < 4; ++ni)
          acc[mi][ni] =
              __builtin_amdgcn_mfma_f32_16x16x32_bf16(af[mi], bfr[ni], acc[mi][ni], 0, 0, 0);
    }
    __syncthreads();
  }

  if constexpr (MODE == 0) {
    const int which = n0 >> 10;  // 0=q 1=k 2=v (block never straddles a 1024 boundary)
    u16* TB = SH;                // bounce: [128][136] u16 = 34816B
    if (which < 2) {
      const float c0 = 0.18033688011112043f;  // log2(e)/8, folded into q
#pragma unroll
      for (int mi = 0; mi < 4; ++mi) {
        const int mb = wr * 64 + mi * 16 + ((lane >> 4) << 2);
#pragma unroll
        for (int ni = 0; ni < 4; ++ni) {
          const int nl = wc * 64 + ni * 16 + (lane & 15);
          const int d = (n0 + nl) & 63;
          const float sgn = (d & 1) ? 1.0f : -1.0f;
#pragma unroll
          for (int rr = 0; rr < 4; ++rr) {
            float v = acc[mi][ni][rr];
            float vp = __shfl_xor(v, 1);  // RoPE partner d^1 at lane^1
            int tg = (m0 + mb + rr) & 2047;
            float2 cs = rt[tg * 32 + (d & 31)];
            float rv = v * cs.x + sgn * vp * cs.y;
            if (which == 0) rv *= c0;
            TB[(mb + rr) * 136 + nl] = f2bf(rv);
          }
        }
      }
      __syncthreads();
      const int m = tid >> 1, halfc = tid & 1;
      u16* dst = (which == 0 ? qb : kb) + (size_t)(m0 + m) * 1024 + (n0 & 1023) + halfc * 64;
      const u16* src = TB + m * 136 + halfc * 64;
#pragma unroll
      for (int j = 0; j < 8; ++j) *(uint4*)(dst + j * 8) = *(const uint4*)(src + j * 8);
    } else {
      // v: transpose in LDS -> TB[n][m], packed along m
#pragma unroll
      for (int mi = 0; mi < 4; ++mi) {
        const int mb = wr * 64 + mi * 16 + ((lane >> 4) << 2);
#pragma unroll
        for (int ni = 0; ni < 4; ++ni) {
          const int nl = wc * 64 + ni * 16 + (lane & 15);
          uint2 w = make_uint2(pk2bf(acc[mi][ni][0], acc[mi][ni][1]),
                               pk2bf(acc[mi][ni][2], acc[mi][ni][3]));
          *(uint2*)(TB + nl * 136 + mb) = w;
        }
      }
      __syncthreads();
      const int nrow = tid >> 1, halfc = tid & 1;
      const int d = nrow & 63;
      const int hI = ((n0 - 2048) >> 6) + (nrow >> 6);
      const int bI = m0 >> 11;
      const int tb0 = (m0 & 2047) + halfc * 64;
      u16* dst = vb + ((size_t)((bI * NH + hI) * HD + d)) * TSEQ + tb0;
      const u16* src = TB + nrow * 136 + halfc * 64;
#pragma unroll
      for (int j = 0; j < 8; ++j) *(uint4*)(dst + j * 8) = *(const uint4*)(src + j * 8);
    }
  } else {
#pragma unroll
    for (int mi = 0; mi < 4; ++mi) {
      const int m = m0 + wr * 64 + mi * 16 + ((lane >> 4) << 2);
#pragma unroll
      for (int ni = 0; ni < 4; ++ni) {
        const int n = n0 + wc * 64 + ni * 16 + (lane & 15);
#pragma unroll
        for (int rr = 0; rr < 4; ++rr) outF[(size_t)(m + rr) * N + n] = acc[mi][ni][rr];
      }
    }
  }
}

// ---------------- flash attention: 32x32x16 MFMA, P in registers ----------------
// grid 512, 4-wave blocks (128 q-rows). Bijective XCD swizzle: XCD x owns bh in
// [4x,4x+4) (K+V = 2MB < 4MB L2/XCD). KVBLK=128: one barrier pair per 128 KV
// rows (R10 lesson: per-iter vmcnt(0)+barrier drain was the dominant stall;
// halve the drain count, double compute per drain). K staged as [128][64],
// V as 2x[64][64]. Swapped QK^T (mfma(K,Q)); cvt_pk+permlane32_swap builds PV
// A-frags in-register (no P LDS). Q pre-scaled by log2(e)/8 => p=exp2(s), no
// max-sub (|s|<~10). Denominator via ones-MFMA (same C layout as o ->
// elementwise normalize). No setprio (m190/R10: hurts lockstep structures).
__global__ __launch_bounds__(256, 2) void k_attn(const u16* __restrict__ qbuf,
                                                 const u16* __restrict__ kbuf,
                                                 const u16* __restrict__ vbuf,
                                                 u16* __restrict__ ybuf) {
  __shared__ __align__(16) u16 Kl[2][128 * 64];
  __shared__ __align__(16) u16 Vl[2][2][64 * 64];
  const int tid = threadIdx.x, lane = tid & 63, wv = tid >> 6;
  const int di = blockIdx.x;
  const int bh = (di & 7) * 4 + ((di >> 3) & 3);  // XCD x handles bh in [4x, 4x+4)
  const int qt = di >> 5;                         // [0,16)
  const int b = bh >> 4, h = bh & 15;
  const int l31 = lane & 31, hi = lane >> 5;

  const u16* qrow = qbuf + (size_t)(b * TSEQ + qt * 128 + wv * 32 + l31) * 1024 + h * HD;
  const u16* kbase = kbuf + (size_t)b * TSEQ * 1024 + h * HD;  // rows t, stride 1024
  const u16* vbase = vbuf + (size_t)bh * HD * TSEQ;            // rows d, stride 2048

  bf16x8 qf[4];  // B-frag slices of this lane's q-row (q = l31)
#pragma unroll
  for (int s = 0; s < 4; ++s) qf[s] = *(const bf16x8*)(qrow + s * 16 + hi * 8);

  bf16x8 vones;  // all-ones B operand for the denominator MFMA
  {
    u32 o1 = 0x3F803F80u;  // bf16 1.0 packed
    u32* w = (u32*)&vones;
    w[0] = o1; w[1] = o1; w[2] = o1; w[3] = o1;
  }

  f32x16 o[2] = {};  // O[q][d]: col=d=dt*32+l31, row=q=(reg&3)+8*(reg>>2)+4*hi
  f32x16 den = {};   // denominator, same row layout (cols replicated)

  stage_rows<4, 256>(kbase, 1024, 0, 0, Kl[0], tid);
  stage_rows<2, 256>(vbase, TSEQ, 0, 0, Vl[0][0], tid);
  stage_rows<2, 256>(vbase, TSEQ, 0, 64, Vl[0][1], tid);
  __syncthreads();

  for (int it = 0; it < 16; ++it) {
    const int cur = it & 1;
    if (it < 15) {
      stage_rows<4, 256>(kbase, 1024, (it + 1) * 128, 0, Kl[cur ^ 1], tid);
      stage_rows<2, 256>(vbase, TSEQ, 0, (it + 1) * 128, Vl[cur ^ 1][0], tid);
      stage_rows<2, 256>(vbase, TSEQ, 0, (it + 1) * 128 + 64, Vl[cur ^ 1][1], tid);
    }
#pragma unroll
    for (int half = 0; half < 2; ++half) {
      bf16x8 pa[4];  // PV A-frags, pa[s] covers kv = half*64 + s*16 .. +15
#pragma unroll
      for (int kvt = 0; kvt < 2; ++kvt) {
        // S^T tile: rows = kv (half*64 + kvt*32 ..+31), cols = q
        f32x16 sa = {};
#pragma unroll
        for (int s = 0; s < 4; ++s) {
          int r = half * 64 + kvt * 32 + l31;
          int ch = (s * 2 + hi) ^ (r & 7);
          bf16x8 kf = *(const bf16x8*)((const char*)Kl[cur] + r * 128 + ch * 16);
          sa = __builtin_amdgcn_mfma_f32_32x32x16_bf16(kf, qf[s], sa, 0, 0, 0);
        }
        float p[16];
#pragma unroll
        for (int r = 0; r < 16; ++r) p[r] = exp2f(sa[r]);
#pragma unroll
        for (int s2 = 0; s2 < 2; ++s2) {
          const int pb = s2 * 8;
          u32 x = pk2bf(p[pb + 0], p[pb + 1]);
          u32 x2 = pk2bf(p[pb + 2], p[pb + 3]);
          u32 y = pk2bf(p[pb + 4], p[pb + 5]);
          u32 y2 = pk2bf(p[pb + 6], p[pb + 7]);
          pl_swap(x, y);
          pl_swap(x2, y2);
          bf16x8 frag;
          u32* fw = (u32*)&frag;
          fw[0] = x;
          fw[1] = x2;
          fw[2] = y;
          fw[3] = y2;
          pa[kvt * 2 + s2] = frag;
        }
      }
      // O += P V (B-frag from Vl[cur][half]: V^T rows = d, kv contiguous); den += P*ones
#pragma unroll
      for (int dt = 0; dt < 2; ++dt)
#pragma unroll
        for (int s = 0; s < 4; ++s) {
          int r = dt * 32 + l31;
          int ch = (s * 2 + hi) ^ (r & 7);
          bf16x8 vf = *(const bf16x8*)((const char*)Vl[cur][half] + r * 128 + ch * 16);
          o[dt] = __builtin_amdgcn_mfma_f32_32x32x16_bf16(pa[s], vf, o[dt], 0, 0, 0);
        }
#pragma unroll
      for (int s = 0; s < 4; ++s)
        den = __builtin_amdgcn_mfma_f32_32x32x16_bf16(pa[s], vones, den, 0, 0, 0);
    }
    __syncthreads();
  }
  // elementwise normalize + store y[b,t,h*64+d] bf16 (den has same row layout as o)
#pragma unroll
  for (int reg = 0; reg < 16; ++reg) {
    const int q = (reg & 3) + 8 * (reg >> 2) + 4 * hi;
    const float inv = 1.0f / den[reg];
    const int tq = qt * 128 + wv * 32 + q;
    const size_t rowb = ((size_t)b * TSEQ + tq) * 1024 + h * HD + l31;
    ybuf[rowb] = f2bf(o[0][reg] * inv);
    ybuf[rowb + 32] = f2bf(o[1][reg] * inv);
  }
}

extern "C" void kernel_launch(void* const* d_in, const int* in_sizes, int n_in, void* d_out,
                              int out_size, void* d_ws, size_t ws_size, hipStream_t stream) {
  const float* x = (const float*)d_in[0];     // [2,2048,1024]
  const float* wqkv = (const float*)d_in[1];  // [1024,3072]
  const float* wout = (const float*)d_in[2];  // [1024,1024]
  float* out = (float*)d_out;                 // [2,2048,1024] fp32
  char* ws = (char*)d_ws;

  u16* xb = (u16*)(ws);                     //  8 MB  x bf16 [4096][1024]
  u16* wqkvT = (u16*)(ws + (8ull << 20));   //  6 MB  w_qkv^T bf16 [3072][1024]
  u16* woutT = (u16*)(ws + (14ull << 20));  //  2 MB  w_out^T bf16 [1024][1024]
  u16* qb = (u16*)(ws + (16ull << 20));     //  8 MB  q [b,t,1024] roped+prescaled
  u16* kb = (u16*)(ws + (24ull << 20));     //  8 MB  k [b,t,1024] roped
  u16* vb = (u16*)(ws + (32ull << 20));     //  8 MB  v [b,h,d,t]
  u16* yb = (u16*)(ws + (40ull << 20));     //  8 MB  y [b,t,h*d]
  // rope table aliases the head of the yb region: consumed by k_gemm<0>, which
  // completes before k_attn writes yb (stream-ordered).
  float2* rt = (float2*)(ws + (40ull << 20));  // 512 KB [2048][32]

  k_f32_to_bf16<<<4096, 256, 0, stream>>>(x, xb, 1048576);
  k_rope_tab<<<256, 256, 0, stream>>>(rt);
  k_transpose_bf16<<<dim3(48, 16), 256, 0, stream>>>(wqkv, wqkvT, 1024, 3072);
  k_transpose_bf16<<<dim3(16, 16), 256, 0, stream>>>(wout, woutT, 1024, 1024);
  k_gemm<0><<<dim3(24, 32), 256, 0, stream>>>(xb, wqkvT, nullptr, qb, kb, vb, rt, 3072);
  k_attn<<<512, 256, 0, stream>>>(qb, kb, vb, yb);
  k_gemm<1><<<dim3(8, 32), 256, 0, stream>>>(yb, woutT, out, nullptr, nullptr, nullptr, nullptr,
                                             1024);
}

// Round 13
// 199.298 us; speedup vs baseline: 1.0424x; 1.0424x over previous
//
#include <hip/hip_runtime.h>

typedef unsigned short u16;
typedef unsigned int u32;
typedef float f32x4 __attribute__((ext_vector_type(4)));
typedef float f32x16 __attribute__((ext_vector_type(16)));
typedef unsigned int u32x2 __attribute__((ext_vector_type(2)));
typedef __bf16 bf16x8 __attribute__((ext_vector_type(8)));

using gas_ptr = const __attribute__((address_space(1))) void*;
using las_ptr = __attribute__((address_space(3))) void*;

#define NH 16
#define HD 64
#define TSEQ 2048

__device__ __forceinline__ u16 f2bf(float f) {
  return __builtin_bit_cast(u16, (__bf16)f);  // v_cvt RNE (pk-fusable)
}
__device__ __forceinline__ u32 pk2bf(float a, float b) {
  return (u32)f2bf(a) | ((u32)f2bf(b) << 16);
}
// exchange: upper-32-lanes of a <-> lower-32-lanes of b (T12 recipe)
__device__ __forceinline__ void pl_swap(u32& a, u32& b) {
  auto r = __builtin_amdgcn_permlane32_swap(a, b, false, false);
  u32x2 rv = __builtin_bit_cast(u32x2, r);
  a = rv[0];
  b = rv[1];
}

// Stage a (NI*THREADS/8)-row x 64-bf16 tile: NI*THREADS 16B-chunks. LDS dest
// linear; global source pre-swizzled with chunk ^= (row&7) so a swizzled
// ds_read is conflict-free (rule #21: both-sides-or-neither).
template <int NI, int THREADS = 256>
__device__ __forceinline__ void stage_rows(const u16* __restrict__ src, size_t rstride,
                                           int row0, int col0, u16* lbuf, int tid) {
#pragma unroll
  for (int i = 0; i < NI; ++i) {
    int p = i * THREADS + tid;
    int r = p >> 3, cst = p & 7;
    int csrc = cst ^ (r & 7);
    const u16* g = src + (size_t)(row0 + r) * rstride + col0 + csrc * 8;
    char* l = (char*)lbuf + (size_t)(i * THREADS + (tid & ~63)) * 16;  // wave-uniform base
    __builtin_amdgcn_global_load_lds((gas_ptr)g, (las_ptr)l, 16, 0, 0);
  }
}

// ---------------- conversion kernels ----------------
__global__ void k_f32_to_bf16(const float* __restrict__ in, u16* __restrict__ out, int n4) {
  int i = blockIdx.x * blockDim.x + threadIdx.x;
  if (i >= n4) return;
  float4 v = ((const float4*)in)[i];
  ((uint2*)out)[i] = make_uint2(pk2bf(v.x, v.y), pk2bf(v.z, v.w));
}

// rope table: [t][j] -> (cos, sin) of t * 10000^(-j/32)
__global__ void k_rope_tab(float2* __restrict__ tab) {
  int i = blockIdx.x * 256 + threadIdx.x;  // 65536 = 2048*32
  int t = i >> 5, j = i & 31;
  float inv = exp2f(-(float)j * 0.41524101186092028f);  // log2(1e4)/32
  float s, c;
  sincosf((float)t * inv, &s, &c);
  tab[i] = make_float2(c, s);
}

// in: [R][C] f32  ->  out: [C][R] bf16   (64x64 tiles)
__global__ void k_transpose_bf16(const float* __restrict__ in, u16* __restrict__ out,
                                 int R, int C) {
  __shared__ u16 lds[64 * 68];
  const int t = threadIdx.x;
  const int c0 = blockIdx.x * 64, r0 = blockIdx.y * 64;
  const int fc = (t & 15) * 4;
#pragma unroll
  for (int p = 0; p < 4; ++p) {
    int r = p * 16 + (t >> 4);
    float4 v = *(const float4*)&in[(size_t)(r0 + r) * C + c0 + fc];
    *(uint2*)&lds[r * 68 + fc] = make_uint2(pk2bf(v.x, v.y), pk2bf(v.z, v.w));
  }
  __syncthreads();
#pragma unroll
  for (int p = 0; p < 16; ++p) {
    int c = p * 4 + (t >> 6);
    int r = t & 63;
    out[(size_t)(c0 + c) * R + r0 + r] = lds[r * 68 + c];
  }
}

// ---------------- GEMM: C[M][N] = A[M][K=1024] * B^T  (B stored [N][K]) ----------------
// MODE 0: QKV projection. Epilogue bounces through LDS for coalesced stores:
//   q -> [b,t,1024] row-major with RoPE applied and pre-scaled by log2(e)/8
//   k -> [b,t,1024] row-major with RoPE
//   v -> [b,h,d,t]  (transposed in LDS, 128B-run stores)
// MODE 1: plain fp32 store to outF[M][N].
template <int MODE>
__global__ __launch_bounds__(256, 2) void k_gemm(const u16* __restrict__ A,
                                                 const u16* __restrict__ B,
                                                 float* __restrict__ outF,
                                                 u16* __restrict__ qb, u16* __restrict__ kb,
                                                 u16* __restrict__ vb,
                                                 const float2* __restrict__ rt, int N) {
  __shared__ __align__(16) u16 SH[32768];  // 64KB: staging dbuf; reused as bounce buffer
  u16* Alb = SH;          // [2][128*64]
  u16* Blb = SH + 16384;  // [2][128*64]
  const int tid = threadIdx.x;
  const int lane = tid & 63;
  const int wv = tid >> 6, wr = wv >> 1, wc = wv & 1;
  const int m0 = blockIdx.y * 128, n0 = blockIdx.x * 128;

  f32x4 acc[4][4] = {};

  stage_rows<4>(A, 1024, m0, 0, Alb, tid);
  stage_rows<4>(B, 1024, n0, 0, Blb, tid);
  __syncthreads();

  for (int kt = 0; kt < 16; ++kt) {
    const int cur = kt & 1;
    if (kt < 15) {
      stage_rows<4>(A, 1024, m0, (kt + 1) * 64, Alb + (cur ^ 1) * 8192, tid);
      stage_rows<4>(B, 1024, n0, (kt + 1) * 64, Blb + (cur ^ 1) * 8192, tid);
    }
#pragma unroll
    for (int ks = 0; ks < 2; ++ks) {
      bf16x8 af[4], bfr[4];
#pragma unroll
      for (int mi = 0; mi < 4; ++mi) {
        int r = wr * 64 + mi * 16 + (lane & 15);
        int ch = (ks * 4 + (lane >> 4)) ^ (r & 7);
        af[mi] = *(const bf16x8*)((const char*)(Alb + cur * 8192) + r * 128 + ch * 16);
      }
#pragma unroll
      for (int ni = 0; ni < 4; ++ni) {
        int r = wc * 64 + ni * 16 + (lane & 15);
        int ch = (ks * 4 + (lane >> 4)) ^ (r & 7);
        bfr[ni] = *(const bf16x8*)((const char*)(Blb + cur * 8192) + r * 128 + ch * 16);
      }
#pragma unroll
      for (int mi = 0; mi < 4; ++mi)
#pragma unroll
        for (int ni = 0; ni < 4; ++ni)
          acc[mi][ni] =
              __builtin_amdgcn_mfma_f32_16x16x32_bf16(af[mi], bfr[ni], acc[mi][ni], 0, 0, 0);
    }
    __syncthreads();
  }

  if constexpr (MODE == 0) {
    const int which = n0 >> 10;  // 0=q 1=k 2=v (block never straddles a 1024 boundary)
    u16* TB = SH;                // bounce: [128][136] u16 = 34816B
    if (which < 2) {
      const float c0 = 0.18033688011112043f;  // log2(e)/8, folded into q
#pragma unroll
      for (int mi = 0; mi < 4; ++mi) {
        const int mb = wr * 64 + mi * 16 + ((lane >> 4) << 2);
#pragma unroll
        for (int ni = 0; ni < 4; ++ni) {
          const int nl = wc * 64 + ni * 16 + (lane & 15);
          const int d = (n0 + nl) & 63;
          const float sgn = (d & 1) ? 1.0f : -1.0f;
#pragma unroll
          for (int rr = 0; rr < 4; ++rr) {
            float v = acc[mi][ni][rr];
            float vp = __shfl_xor(v, 1);  // RoPE partner d^1 at lane^1
            int tg = (m0 + mb + rr) & 2047;
            float2 cs = rt[tg * 32 + (d & 31)];
            float rv = v * cs.x + sgn * vp * cs.y;
            if (which == 0) rv *= c0;
            TB[(mb + rr) * 136 + nl] = f2bf(rv);
          }
        }
      }
      __syncthreads();
      const int m = tid >> 1, halfc = tid & 1;
      u16* dst = (which == 0 ? qb : kb) + (size_t)(m0 + m) * 1024 + (n0 & 1023) + halfc * 64;
      const u16* src = TB + m * 136 + halfc * 64;
#pragma unroll
      for (int j = 0; j < 8; ++j) *(uint4*)(dst + j * 8) = *(const uint4*)(src + j * 8);
    } else {
      // v: transpose in LDS -> TB[n][m], packed along m
#pragma unroll
      for (int mi = 0; mi < 4; ++mi) {
        const int mb = wr * 64 + mi * 16 + ((lane >> 4) << 2);
#pragma unroll
        for (int ni = 0; ni < 4; ++ni) {
          const int nl = wc * 64 + ni * 16 + (lane & 15);
          uint2 w = make_uint2(pk2bf(acc[mi][ni][0], acc[mi][ni][1]),
                               pk2bf(acc[mi][ni][2], acc[mi][ni][3]));
          *(uint2*)(TB + nl * 136 + mb) = w;
        }
      }
      __syncthreads();
      const int nrow = tid >> 1, halfc = tid & 1;
      const int d = nrow & 63;
      const int hI = ((n0 - 2048) >> 6) + (nrow >> 6);
      const int bI = m0 >> 11;
      const int tb0 = (m0 & 2047) + halfc * 64;
      u16* dst = vb + ((size_t)((bI * NH + hI) * HD + d)) * TSEQ + tb0;
      const u16* src = TB + nrow * 136 + halfc * 64;
#pragma unroll
      for (int j = 0; j < 8; ++j) *(uint4*)(dst + j * 8) = *(const uint4*)(src + j * 8);
    }
  } else {
#pragma unroll
    for (int mi = 0; mi < 4; ++mi) {
      const int m = m0 + wr * 64 + mi * 16 + ((lane >> 4) << 2);
#pragma unroll
      for (int ni = 0; ni < 4; ++ni) {
        const int n = n0 + wc * 64 + ni * 16 + (lane & 15);
#pragma unroll
        for (int rr = 0; rr < 4; ++rr) outF[(size_t)(m + rr) * N + n] = acc[mi][ni][rr];
      }
    }
  }
}

// ---------------- flash attention: 32x32x16 MFMA, P in registers, KV-split ----------------
// grid 512 x 512 threads (8 waves). Waves 0-3 process KV[0,1024), waves 4-7
// KV[1024,2048) for the SAME 128 q-rows; no-max softmax => partials combine by
// pure summation (o and psum add, no rescale) in LDS at block end. 16 waves/CU
// = 4 waves/SIMD (R12 lesson: 2 waves/SIMD left the serial chain exposed).
// Per half: KVBLK=64 double-buffered (64KB LDS total, 2 blocks/CU = 128KB).
// Swapped QK^T (mfma(K,Q)); cvt_pk+permlane32_swap builds PV A-frags in-register.
// Q pre-scaled by log2(e)/8 => p=exp2(s). Denominator = per-lane psum + one
// shfl_xor(32) (R8 measured best; den-MFMA reverted: +5us in R10/R12 A/B).
__global__ __launch_bounds__(512, 4) void k_attn(const u16* __restrict__ qbuf,
                                                 const u16* __restrict__ kbuf,
                                                 const u16* __restrict__ vbuf,
                                                 u16* __restrict__ ybuf) {
  __shared__ __align__(16) u16 SH[32768];  // 64KB: [half][K dbuf 16KB | V dbuf 16KB]
  const int tid = threadIdx.x, lane = tid & 63, wv = tid >> 6;
  const int half = wv >> 2, wvq = wv & 3;  // KV-half; q-wave within half
  const int t2 = tid & 255;                // thread id within the half-group
  const int di = blockIdx.x;
  const int bh = (di & 7) * 4 + ((di >> 3) & 3);  // XCD x handles bh in [4x, 4x+4)
  const int qt = di >> 5;                         // [0,16)
  const int b = bh >> 4, h = bh & 15;
  const int l31 = lane & 31, hi = lane >> 5;

  u16* const KLb = SH + half * 16384;         // K: buf*4096
  u16* const VLb = SH + half * 16384 + 8192;  // V: buf*4096
  const int r0 = half * 1024;                 // this half's KV row offset

  const u16* qrow = qbuf + (size_t)(b * TSEQ + qt * 128 + wvq * 32 + l31) * 1024 + h * HD;
  const u16* kbase = kbuf + (size_t)b * TSEQ * 1024 + h * HD;  // rows t, stride 1024
  const u16* vbase = vbuf + (size_t)bh * HD * TSEQ;            // rows d, stride 2048

  bf16x8 qf[4];  // B-frag slices of this lane's q-row (q = l31)
#pragma unroll
  for (int s = 0; s < 4; ++s) qf[s] = *(const bf16x8*)(qrow + s * 16 + hi * 8);

  f32x16 o[2] = {};  // O[q][d]: col=d=dt*32+l31, row=q=(reg&3)+8*(reg>>2)+4*hi
  float psum = 0.f;  // partial denominator for q=l31 (over this lane's kv regs)

  stage_rows<2, 256>(kbase, 1024, r0, 0, KLb, t2);
  stage_rows<2, 256>(vbase, TSEQ, 0, r0, VLb, t2);
  __syncthreads();

  for (int it = 0; it < 16; ++it) {
    const int cur = it & 1;
    if (it < 15) {
      stage_rows<2, 256>(kbase, 1024, r0 + (it + 1) * 64, 0, KLb + (cur ^ 1) * 4096, t2);
      stage_rows<2, 256>(vbase, TSEQ, 0, r0 + (it + 1) * 64, VLb + (cur ^ 1) * 4096, t2);
    }
    bf16x8 pa[4];  // PV A-frags, pa[s] covers kv = s*16 .. s*16+15 (within tile)
#pragma unroll
    for (int kvt = 0; kvt < 2; ++kvt) {
      // S^T tile: rows = kv (kvt*32..+31), cols = q
      f32x16 sa = {};
#pragma unroll
      for (int s = 0; s < 4; ++s) {
        int r = kvt * 32 + l31;
        int ch = (s * 2 + hi) ^ (r & 7);
        bf16x8 kf = *(const bf16x8*)((const char*)(KLb + cur * 4096) + r * 128 + ch * 16);
        sa = __builtin_amdgcn_mfma_f32_32x32x16_bf16(kf, qf[s], sa, 0, 0, 0);
      }
      float p[16];
#pragma unroll
      for (int r = 0; r < 16; ++r) {
        p[r] = exp2f(sa[r]);
        psum += p[r];
      }
#pragma unroll
      for (int s2 = 0; s2 < 2; ++s2) {
        const int pb = s2 * 8;
        u32 x = pk2bf(p[pb + 0], p[pb + 1]);
        u32 x2 = pk2bf(p[pb + 2], p[pb + 3]);
        u32 y = pk2bf(p[pb + 4], p[pb + 5]);
        u32 y2 = pk2bf(p[pb + 6], p[pb + 7]);
        pl_swap(x, y);
        pl_swap(x2, y2);
        bf16x8 frag;
        u32* fw = (u32*)&frag;
        fw[0] = x;
        fw[1] = x2;
        fw[2] = y;
        fw[3] = y2;
        pa[kvt * 2 + s2] = frag;
      }
    }
    // O += P V (B-frag from VL: V^T rows = d, kv contiguous)
#pragma unroll
    for (int dt = 0; dt < 2; ++dt)
#pragma unroll
      for (int s = 0; s < 4; ++s) {
        int r = dt * 32 + l31;
        int ch = (s * 2 + hi) ^ (r & 7);
        bf16x8 vf = *(const bf16x8*)((const char*)(VLb + cur * 4096) + r * 128 + ch * 16);
        o[dt] = __builtin_amdgcn_mfma_f32_32x32x16_bf16(pa[s], vf, o[dt], 0, 0, 0);
      }
    __syncthreads();
  }

  // cross-half combine in LDS (reuse staging space): record = 32 o + 1 psum floats
  float* sc = (float*)SH;  // 4 waves x 64 lanes x 33 f32 = 33.8KB <= 64KB
  if (half == 1) {
    float* rec = sc + (wvq * 64 + lane) * 33;
#pragma unroll
    for (int dt = 0; dt < 2; ++dt)
#pragma unroll
      for (int reg = 0; reg < 16; ++reg) rec[dt * 16 + reg] = o[dt][reg];
    rec[32] = psum;
  }
  __syncthreads();
  if (half == 0) {
    const float* rec = sc + (wvq * 64 + lane) * 33;
#pragma unroll
    for (int dt = 0; dt < 2; ++dt)
#pragma unroll
      for (int reg = 0; reg < 16; ++reg) o[dt][reg] += rec[dt * 16 + reg];
    psum += rec[32];
    psum += __shfl_xor(psum, 32);
    float pinv = 1.0f / psum;  // valid for q = l31 on every lane
#pragma unroll
    for (int reg = 0; reg < 16; ++reg) {
      const int q = (reg & 3) + 8 * (reg >> 2) + 4 * hi;
      const float inv = __shfl(pinv, q);
      const int tq = qt * 128 + wvq * 32 + q;
      const size_t rowb = ((size_t)b * TSEQ + tq) * 1024 + h * HD + l31;
      ybuf[rowb] = f2bf(o[0][reg] * inv);
      ybuf[rowb + 32] = f2bf(o[1][reg] * inv);
    }
  }
}

extern "C" void kernel_launch(void* const* d_in, const int* in_sizes, int n_in, void* d_out,
                              int out_size, void* d_ws, size_t ws_size, hipStream_t stream) {
  const float* x = (const float*)d_in[0];     // [2,2048,1024]
  const float* wqkv = (const float*)d_in[1];  // [1024,3072]
  const float* wout = (const float*)d_in[2];  // [1024,1024]
  float* out = (float*)d_out;                 // [2,2048,1024] fp32
  char* ws = (char*)d_ws;

  u16* xb = (u16*)(ws);                     //  8 MB  x bf16 [4096][1024]
  u16* wqkvT = (u16*)(ws + (8ull << 20));   //  6 MB  w_qkv^T bf16 [3072][1024]
  u16* woutT = (u16*)(ws + (14ull << 20));  //  2 MB  w_out^T bf16 [1024][1024]
  u16* qb = (u16*)(ws + (16ull << 20));     //  8 MB  q [b,t,1024] roped+prescaled
  u16* kb = (u16*)(ws + (24ull << 20));     //  8 MB  k [b,t,1024] roped
  u16* vb = (u16*)(ws + (32ull << 20));     //  8 MB  v [b,h,d,t]
  u16* yb = (u16*)(ws + (40ull << 20));     //  8 MB  y [b,t,h*d]
  // rope table aliases the head of the yb region: consumed by k_gemm<0>, which
  // completes before k_attn writes yb (stream-ordered).
  float2* rt = (float2*)(ws + (40ull << 20));  // 512 KB [2048][32]

  k_f32_to_bf16<<<4096, 256, 0, stream>>>(x, xb, 1048576);
  k_rope_tab<<<256, 256, 0, stream>>>(rt);
  k_transpose_bf16<<<dim3(48, 16), 256, 0, stream>>>(wqkv, wqkvT, 1024, 3072);
  k_transpose_bf16<<<dim3(16, 16), 256, 0, stream>>>(wout, woutT, 1024, 1024);
  k_gemm<0><<<dim3(24, 32), 256, 0, stream>>>(xb, wqkvT, nullptr, qb, kb, vb, rt, 3072);
  k_attn<<<512, 512, 0, stream>>>(qb, kb, vb, yb);
  k_gemm<1><<<dim3(8, 32), 256, 0, stream>>>(yb, woutT, out, nullptr, nullptr, nullptr, nullptr,
                                             1024);
}